// Round 7
// baseline (488.994 us; speedup 1.0000x reference)
//
#include <hip/hip_runtime.h>

#define B_    8
#define V_    50000
#define KNB   9
#define CIN_  64
#define COUT_ 128
#define VOUT_ 12500
#define NNZ_  37500
#define KTOT  576      // KNB*CIN_
#define M_    400000   // B_*V_
#define NWG   3125     // M_/128

typedef short bf16x8 __attribute__((ext_vector_type(8)));
typedef float f32x4  __attribute__((ext_vector_type(4)));

#define AS1 __attribute__((address_space(1)))
#define AS3 __attribute__((address_space(3)))

__device__ __forceinline__ unsigned short f2bf(float f) {
  unsigned u = __float_as_uint(f);
  u += 0x7fffu + ((u >> 16) & 1u);          // RNE
  return (unsigned short)(u >> 16);
}
__device__ __forceinline__ float bf2f(unsigned short u) {
  return __uint_as_float((unsigned)u << 16);
}

__device__ __forceinline__ void gld_lds16(const void* g, void* l) {
  __builtin_amdgcn_global_load_lds((const AS1 unsigned*)g, (AS3 unsigned*)l, 16, 0, 0);
}

// Fused prep: blockIdx [0,36) convert W->frag-major; [36,183) pool_count;
// [183,2231) convert x fp32->bf16 (grid-stride).
#define PREP_WBLK 36
#define PREP_CBLK 147
#define PREP_XBLK 2048
__global__ __launch_bounds__(256) void prep(const float* __restrict__ w,
                                            unsigned short* __restrict__ wfr,
                                            const float* __restrict__ x,
                                            unsigned short* __restrict__ xbf,
                                            const int* __restrict__ dr,
                                            int* __restrict__ counts) {
  const int bid = blockIdx.x;
  if (bid < PREP_WBLK) {
    // W -> MFMA-fragment-major bf16: chunk i holds, for lane=i&63, n=(i>>6)&3,
    // wc=(i>>8)&1, ks=(i>>9)&1, t=i>>10:
    //   W[col=wc*64+n*16+(lane&15)][k=t*64+ks*32+(lane>>4)*8 .. +8]
    int i = bid * 256 + threadIdx.x;        // 0..9215
    int lane = i & 63, n = (i >> 6) & 3, wc = (i >> 8) & 1, ks = (i >> 9) & 1, t = i >> 10;
    int col = wc * 64 + n * 16 + (lane & 15);
    int k0 = t * 64 + ks * 32 + (lane >> 4) * 8;
    const float* src = w + (size_t)col * KTOT + k0;
    float4 f0 = reinterpret_cast<const float4*>(src)[0];
    float4 f1 = reinterpret_cast<const float4*>(src)[1];
    uint4 o;
    o.x = (unsigned)f2bf(f0.x) | ((unsigned)f2bf(f0.y) << 16);
    o.y = (unsigned)f2bf(f0.z) | ((unsigned)f2bf(f0.w) << 16);
    o.z = (unsigned)f2bf(f1.x) | ((unsigned)f2bf(f1.y) << 16);
    o.w = (unsigned)f2bf(f1.z) | ((unsigned)f2bf(f1.w) << 16);
    reinterpret_cast<uint4*>(wfr)[i] = o;
  } else if (bid < PREP_WBLK + PREP_CBLK) {
    int e = (bid - PREP_WBLK) * 256 + threadIdx.x;
    if (e < NNZ_) atomicAdd(&counts[dr[e]], 1);
  } else {
    const int nq = B_ * V_ * CIN_ / 4;      // 6.4M float4 quads
    for (int q = (bid - PREP_WBLK - PREP_CBLK) * 256 + threadIdx.x; q < nq;
         q += PREP_XBLK * 256) {
      float4 f = reinterpret_cast<const float4*>(x)[q];
      ushort4 o;
      o.x = f2bf(f.x); o.y = f2bf(f.y); o.z = f2bf(f.z); o.w = f2bf(f.w);
      reinterpret_cast<ushort4*>(xbf)[q] = o;
    }
  }
}

// h = elu(gather(x) @ W^T + bias). 128x128 tile, 4 waves (2x2 of 64x64), BK=64.
// A-only LDS double buffer (exactly 32KB -> 5 blocks/CU, 20 waves), JIT B-frag
// register loads from L1/L2, rolling idx prefetch, one __syncthreads per K-step.
// Epilogue reuses the same 32KB as hs[128][256B] with XOR-16B swizzle (no pad).
// Bijective XCD swizzle confines each XCD's random gather for L2 locality.
__global__ __launch_bounds__(256, 5) void spiral_gemm(
    const unsigned short* __restrict__ xbf, const unsigned short* __restrict__ wfr,
    const float* __restrict__ bias, const int* __restrict__ sp,
    unsigned short* __restrict__ hbf)
{
  __shared__ char smem[32768];     // A: 2 x 16KB; epilogue: hs 128 rows x 256B

  // ---- bijective XCD swizzle (nwg=3125: q=390, r=5)
  const int q_ = NWG / 8, r_ = NWG % 8;
  const int xcd = blockIdx.x & 7, pos = blockIdx.x >> 3;
  const int nbid = (xcd < r_) ? xcd * (q_ + 1) + pos
                              : r_ * (q_ + 1) + (xcd - r_) * q_ + pos;

  const int tid  = threadIdx.x;
  const int m0   = nbid * 128;
  const int wave = tid >> 6;
  const int lane = tid & 63;

  // ---- staging geometry: 4 rounds x 32 rows, 8 lanes x 16B chunks per 128B row
  const int rrow  = tid >> 3;                       // 0..31
  const int chunkoff = (((tid & 7) ^ (rrow & 7)) << 4); // inverse-swizzled source chunk

  unsigned boff[4];
  const int* spb[4];
  #pragma unroll
  for (int r = 0; r < 4; ++r) {
    int row = r * 32 + rrow;
    int m = m0 + row;
    int b = m / V_;
    int v = m - b * V_;
    boff[r] = (unsigned)b * (V_ * CIN_ * 2);        // byte offset of batch slice
    spb[r]  = sp + v * KNB;
  }

  // ---- compute geometry
  const int wr = wave >> 1, wc = wave & 1;
  const int lr = lane & 15, lg = lane >> 4;
  const bf16x8* wbase = (const bf16x8*)wfr + wc * 256 + lane;   // +((t*2+ks)*512 + n*64)

  f32x4 acc[4][4];
  #pragma unroll
  for (int i = 0; i < 4; ++i)
    #pragma unroll
    for (int j = 0; j < 4; ++j)
      acc[i][j] = (f32x4){0.f, 0.f, 0.f, 0.f};

  auto stageA = [&](char* Ab, const int (&idx)[4]) {
    #pragma unroll
    for (int r = 0; r < 4; ++r) {
      unsigned off = boff[r] + (unsigned)idx[r] * 128u + (unsigned)chunkoff;
      gld_lds16((const char*)xbf + off, Ab + (r * 32 + wave * 8) * 128);
    }
  };

  // ---- prologue: stage t=0, preload idx for t=1
  int idx[4];
  #pragma unroll
  for (int r = 0; r < 4; ++r) idx[r] = spb[r][0];
  stageA(smem, idx);
  #pragma unroll
  for (int r = 0; r < 4; ++r) idx[r] = spb[r][1];
  __syncthreads();      // drains vmcnt(0): A(0) staged & visible

  // ---- main loop: one syncthreads per K-step; rolled so idx loads stay rolling
  #pragma unroll 1
  for (int t = 0; t < KNB; ++t) {
    if (t + 1 < KNB) stageA(smem + 16384 * ((t + 1) & 1), idx);
    if (t + 2 < KNB) {
      #pragma unroll
      for (int r = 0; r < 4; ++r) idx[r] = spb[r][t + 2];
    }
    const char* Ab = smem + 16384 * (t & 1);
    #pragma unroll
    for (int ks = 0; ks < 2; ++ks) {
      // B(t,ks) fragments JIT from L1/L2 (16 regs live)
      bf16x8 breg[4];
      #pragma unroll
      for (int n = 0; n < 4; ++n)
        breg[n] = wbase[(t * 2 + ks) * 512 + n * 64];
      const int kb = ks * 64 + lg * 16;
      bf16x8 af[4];
      #pragma unroll
      for (int m = 0; m < 4; ++m) {
        int row = wr * 64 + m * 16 + lr;
        af[m] = *reinterpret_cast<const bf16x8*>(Ab + row * 128 + (kb ^ ((row & 7) << 4)));
      }
      __builtin_amdgcn_s_setprio(1);
      #pragma unroll
      for (int m = 0; m < 4; ++m)
        #pragma unroll
        for (int n = 0; n < 4; ++n)
          acc[m][n] = __builtin_amdgcn_mfma_f32_16x16x32_bf16(af[m], breg[n], acc[m][n], 0, 0, 0);
      __builtin_amdgcn_s_setprio(0);
    }
    __syncthreads();   // A(t+1) staged & visible; buffer t&1 free for reuse
  }

  // ---- epilogue: bias + ELU -> bf16 into swizzled hs (row*256 + (cb ^ (row&7)<<4)),
  //      then coalesced 16B global stores. Fits exactly in the 32KB double buffer.
  #pragma unroll
  for (int n = 0; n < 4; ++n) {
    const int c = wc * 64 + n * 16 + lr;
    const float bv = bias[c];
    #pragma unroll
    for (int m = 0; m < 4; ++m) {
      const int row0 = wr * 64 + m * 16 + lg * 4;
      #pragma unroll
      for (int j = 0; j < 4; ++j) {
        const int row = row0 + j;
        float vv = acc[m][n][j] + bv;
        vv = vv > 0.f ? vv : (__expf(vv) - 1.f);
        *reinterpret_cast<unsigned short*>(
            smem + row * 256 + ((c * 2) ^ ((row & 7) << 4))) = f2bf(vv);
      }
    }
  }
  __syncthreads();
  const int r2 = tid >> 1, hf = tid & 1;
  uint4* drow = reinterpret_cast<uint4*>(hbf + (size_t)(m0 + r2) * COUT_ + hf * 64);
  #pragma unroll
  for (int u = 0; u < 8; ++u) {
    int cb = hf * 128 + u * 16;
    drow[u] = *reinterpret_cast<const uint4*>(smem + r2 * 256 + (cb ^ ((r2 & 7) << 4)));
  }
}

// ---------------- pool: CSR scan / fill, then row-major gather ----------

__global__ __launch_bounds__(256) void pool_scan(const int* __restrict__ counts,
                                                 int* __restrict__ offsets,
                                                 int* __restrict__ cursor) {
  __shared__ int part[256];
  const int t = threadIdx.x;
  const int c0 = t * 49;
  int s = 0;
  for (int i = 0; i < 49; ++i) {
    int j = c0 + i;
    if (j < VOUT_) s += counts[j];
  }
  part[t] = s;
  __syncthreads();
  #pragma unroll
  for (int off = 1; off < 256; off <<= 1) {
    int v = (t >= off) ? part[t - off] : 0;
    __syncthreads();
    part[t] += v;
    __syncthreads();
  }
  int run = part[t] - s;                 // exclusive prefix of my chunk
  for (int i = 0; i < 49; ++i) {
    int j = c0 + i;
    if (j < VOUT_) {
      offsets[j] = run; cursor[j] = run;
      run += counts[j];
    }
  }
  if (t == 255) offsets[VOUT_] = part[255];   // == NNZ_
}

__global__ __launch_bounds__(256) void pool_fill(const int* __restrict__ dr,
                                                 const int* __restrict__ dc,
                                                 const float* __restrict__ dd,
                                                 int* __restrict__ cursor,
                                                 int2* __restrict__ elist) {
  int e = blockIdx.x * 256 + threadIdx.x;
  if (e < NNZ_) {
    int slot = atomicAdd(&cursor[dr[e]], 1);
    elist[slot] = make_int2(dc[e], __float_as_int(dd[e]));
  }
}

__global__ __launch_bounds__(256) void pool_rows(const unsigned short* __restrict__ hbf,
                                                 const int* __restrict__ offsets,
                                                 const int2* __restrict__ elist,
                                                 float* __restrict__ out) {
  const int row = blockIdx.x;
  const int bg = threadIdx.x >> 5;     // batch 0..7
  const int lc = threadIdx.x & 31;     // c-quad 0..31
  const int s = offsets[row], e1 = offsets[row + 1];
  const unsigned short* hb = hbf + (size_t)bg * (V_ * COUT_) + lc * 4;
  float4 acc = {0.f, 0.f, 0.f, 0.f};
  for (int e = s; e < e1; ++e) {
    int2 en = elist[e];
    float d = __int_as_float(en.y);
    ushort4 v = *reinterpret_cast<const ushort4*>(hb + (size_t)en.x * COUT_);
    acc.x += d * bf2f(v.x);
    acc.y += d * bf2f(v.y);
    acc.z += d * bf2f(v.z);
    acc.w += d * bf2f(v.w);
  }
  *reinterpret_cast<float4*>(out + ((size_t)bg * VOUT_ + row) * COUT_ + lc * 4) = acc;
}

extern "C" void kernel_launch(void* const* d_in, const int* in_sizes, int n_in,
                              void* d_out, int out_size, void* d_ws, size_t ws_size,
                              hipStream_t stream) {
  const float* x    = (const float*)d_in[0];
  const float* w    = (const float*)d_in[1];
  const float* bias = (const float*)d_in[2];
  const int*   sp   = (const int*)d_in[3];
  const int*   dr   = (const int*)d_in[4];
  const int*   dc   = (const int*)d_in[5];
  const float* dd   = (const float*)d_in[6];
  float* out = (float*)d_out;

  char* ws = (char*)d_ws;
  unsigned short* wfr = (unsigned short*)ws;                       // 147,456 B (frag-major)
  unsigned short* xbf = (unsigned short*)(ws + 147456);            // 51,200,000 B
  unsigned short* hbf = (unsigned short*)(ws + 51347456);          // 102,400,000 B
  int*  counts  = (int*) (ws + 153747456);                         // 50,000 B
  int*  cursor  = (int*) (ws + 153797456);                         // 50,000 B
  int*  offsets = (int*) (ws + 153847456);                         // 50,004 B
  int2* elist   = (int2*)(ws + 153897464);                         // 300,000 B

  hipMemsetAsync(counts, 0, VOUT_ * sizeof(int), stream);
  prep<<<PREP_WBLK + PREP_CBLK + PREP_XBLK, 256, 0, stream>>>(w, wfr, x, xbf, dr, counts);
  pool_scan<<<1, 256, 0, stream>>>(counts, offsets, cursor);
  pool_fill<<<(NNZ_ + 255) / 256, 256, 0, stream>>>(dr, dc, dd, cursor, elist);
  spiral_gemm<<<NWG, 256, 0, stream>>>(xbf, wfr, bias, sp, hbf);
  pool_rows<<<VOUT_, 256, 0, stream>>>(hbf, offsets, elist, out);
}

// Round 8
// 196.509 us; speedup vs baseline: 2.4884x; 2.4884x over previous
//
#include <hip/hip_runtime.h>

#define B_    8
#define V_    50000
#define KNB   9
#define CIN_  64
#define COUT_ 128
#define VOUT_ 12500
#define NNZ_  37500
#define KTOT  576      // KNB*CIN_
#define M_    400000   // B_*V_
#define NWG   3125     // M_/128

typedef short bf16x8 __attribute__((ext_vector_type(8)));
typedef float f32x4  __attribute__((ext_vector_type(4)));

#define AS1 __attribute__((address_space(1)))
#define AS3 __attribute__((address_space(3)))

__device__ __forceinline__ unsigned short f2bf(float f) {
  unsigned u = __float_as_uint(f);
  u += 0x7fffu + ((u >> 16) & 1u);          // RNE
  return (unsigned short)(u >> 16);
}
__device__ __forceinline__ float bf2f(unsigned short u) {
  return __uint_as_float((unsigned)u << 16);
}

__device__ __forceinline__ void gld_lds16(const void* g, void* l) {
  __builtin_amdgcn_global_load_lds((const AS1 unsigned*)g, (AS3 unsigned*)l, 16, 0, 0);
}

// Fused prep: blockIdx [0,36) convert W->frag-major; [36,183) pool_count;
// [183,2231) convert x fp32->bf16 (grid-stride).
#define PREP_WBLK 36
#define PREP_CBLK 147
#define PREP_XBLK 2048
__global__ __launch_bounds__(256) void prep(const float* __restrict__ w,
                                            unsigned short* __restrict__ wfr,
                                            const float* __restrict__ x,
                                            unsigned short* __restrict__ xbf,
                                            const int* __restrict__ dr,
                                            int* __restrict__ counts) {
  const int bid = blockIdx.x;
  if (bid < PREP_WBLK) {
    // W -> MFMA-fragment-major bf16: chunk i holds, for lane=i&63, n=(i>>6)&3,
    // wc=(i>>8)&1, ks=(i>>9)&1, t=i>>10:
    //   W[col=wc*64+n*16+(lane&15)][k=t*64+ks*32+(lane>>4)*8 .. +8]
    int i = bid * 256 + threadIdx.x;        // 0..9215
    int lane = i & 63, n = (i >> 6) & 3, wc = (i >> 8) & 1, ks = (i >> 9) & 1, t = i >> 10;
    int col = wc * 64 + n * 16 + (lane & 15);
    int k0 = t * 64 + ks * 32 + (lane >> 4) * 8;
    const float* src = w + (size_t)col * KTOT + k0;
    float4 f0 = reinterpret_cast<const float4*>(src)[0];
    float4 f1 = reinterpret_cast<const float4*>(src)[1];
    uint4 o;
    o.x = (unsigned)f2bf(f0.x) | ((unsigned)f2bf(f0.y) << 16);
    o.y = (unsigned)f2bf(f0.z) | ((unsigned)f2bf(f0.w) << 16);
    o.z = (unsigned)f2bf(f1.x) | ((unsigned)f2bf(f1.y) << 16);
    o.w = (unsigned)f2bf(f1.z) | ((unsigned)f2bf(f1.w) << 16);
    reinterpret_cast<uint4*>(wfr)[i] = o;
  } else if (bid < PREP_WBLK + PREP_CBLK) {
    int e = (bid - PREP_WBLK) * 256 + threadIdx.x;
    if (e < NNZ_) atomicAdd(&counts[dr[e]], 1);
  } else {
    const int nq = B_ * V_ * CIN_ / 4;      // 6.4M float4 quads
    for (int q = (bid - PREP_WBLK - PREP_CBLK) * 256 + threadIdx.x; q < nq;
         q += PREP_XBLK * 256) {
      float4 f = reinterpret_cast<const float4*>(x)[q];
      ushort4 o;
      o.x = f2bf(f.x); o.y = f2bf(f.y); o.z = f2bf(f.z); o.w = f2bf(f.w);
      reinterpret_cast<ushort4*>(xbf)[q] = o;
    }
  }
}

// h = elu(gather(x) @ W^T + bias). 128x128 tile, 4 waves (2x2 of 64x64), BK=64.
// A-only LDS double buffer (exactly 32KB). launch_bounds stays (256,4): the 2nd
// arg is a REGISTER-BUDGET contract (5 would force <=64 VGPR -> acc spills ->
// 962MB scratch traffic, R7 post-mortem). Hardware packs 5 blocks/CU from the
// LDS limit on its own when VGPR<=64.
__global__ __launch_bounds__(256, 4) void spiral_gemm(
    const unsigned short* __restrict__ xbf, const unsigned short* __restrict__ wfr,
    const float* __restrict__ bias, const int* __restrict__ sp,
    unsigned short* __restrict__ hbf)
{
  __shared__ char smem[32768];     // A: 2 x 16KB; epilogue: hs 128 rows x 256B

  // ---- bijective XCD swizzle (nwg=3125: q=390, r=5)
  const int q_ = NWG / 8, r_ = NWG % 8;
  const int xcd = blockIdx.x & 7, pos = blockIdx.x >> 3;
  const int nbid = (xcd < r_) ? xcd * (q_ + 1) + pos
                              : r_ * (q_ + 1) + (xcd - r_) * q_ + pos;

  const int tid  = threadIdx.x;
  const int m0   = nbid * 128;
  const int wave = tid >> 6;
  const int lane = tid & 63;

  // ---- staging geometry: 4 rounds x 32 rows, 8 lanes x 16B chunks per 128B row
  const int rrow  = tid >> 3;                       // 0..31
  const int chunkoff = (((tid & 7) ^ (rrow & 7)) << 4); // inverse-swizzled source chunk

  unsigned boff[4];
  const int* spb[4];
  #pragma unroll
  for (int r = 0; r < 4; ++r) {
    int row = r * 32 + rrow;
    int m = m0 + row;
    int b = m / V_;
    int v = m - b * V_;
    boff[r] = (unsigned)b * (V_ * CIN_ * 2);        // byte offset of batch slice
    spb[r]  = sp + v * KNB;
  }

  // ---- compute geometry
  const int wr = wave >> 1, wc = wave & 1;
  const int lr = lane & 15, lg = lane >> 4;
  const bf16x8* wbase = (const bf16x8*)wfr + wc * 256 + lane;   // +((t*2+ks)*512 + n*64)

  f32x4 acc[4][4];
  #pragma unroll
  for (int i = 0; i < 4; ++i)
    #pragma unroll
    for (int j = 0; j < 4; ++j)
      acc[i][j] = (f32x4){0.f, 0.f, 0.f, 0.f};

  auto stageA = [&](char* Ab, const int (&idx)[4]) {
    #pragma unroll
    for (int r = 0; r < 4; ++r) {
      unsigned off = boff[r] + (unsigned)idx[r] * 128u + (unsigned)chunkoff;
      gld_lds16((const char*)xbf + off, Ab + (r * 32 + wave * 8) * 128);
    }
  };

  // ---- prologue: stage t=0, preload idx for t=1
  int idx[4];
  #pragma unroll
  for (int r = 0; r < 4; ++r) idx[r] = spb[r][0];
  stageA(smem, idx);
  #pragma unroll
  for (int r = 0; r < 4; ++r) idx[r] = spb[r][1];
  __syncthreads();      // drains vmcnt(0): A(0) staged & visible

  // ---- main loop: one syncthreads per K-step; rolled so idx loads stay rolling
  #pragma unroll 1
  for (int t = 0; t < KNB; ++t) {
    if (t + 1 < KNB) stageA(smem + 16384 * ((t + 1) & 1), idx);
    if (t + 2 < KNB) {
      #pragma unroll
      for (int r = 0; r < 4; ++r) idx[r] = spb[r][t + 2];
    }
    const char* Ab = smem + 16384 * (t & 1);
    #pragma unroll
    for (int ks = 0; ks < 2; ++ks) {
      // B(t,ks) fragments JIT from L1/L2 (16 regs live)
      bf16x8 breg[4];
      #pragma unroll
      for (int n = 0; n < 4; ++n)
        breg[n] = wbase[(t * 2 + ks) * 512 + n * 64];
      const int kb = ks * 64 + lg * 16;
      bf16x8 af[4];
      #pragma unroll
      for (int m = 0; m < 4; ++m) {
        int row = wr * 64 + m * 16 + lr;
        af[m] = *reinterpret_cast<const bf16x8*>(Ab + row * 128 + (kb ^ ((row & 7) << 4)));
      }
      __builtin_amdgcn_s_setprio(1);
      #pragma unroll
      for (int m = 0; m < 4; ++m)
        #pragma unroll
        for (int n = 0; n < 4; ++n)
          acc[m][n] = __builtin_amdgcn_mfma_f32_16x16x32_bf16(af[m], breg[n], acc[m][n], 0, 0, 0);
      __builtin_amdgcn_s_setprio(0);
    }
    __syncthreads();   // A(t+1) staged & visible; buffer t&1 free for reuse
  }

  // ---- epilogue: bias + ELU -> bf16 into swizzled hs (row*256 + (cb ^ (row&7)<<4)),
  //      then coalesced 16B global stores. Fits exactly in the 32KB double buffer.
  #pragma unroll
  for (int n = 0; n < 4; ++n) {
    const int c = wc * 64 + n * 16 + lr;
    const float bv = bias[c];
    #pragma unroll
    for (int m = 0; m < 4; ++m) {
      const int row0 = wr * 64 + m * 16 + lg * 4;
      #pragma unroll
      for (int j = 0; j < 4; ++j) {
        const int row = row0 + j;
        float vv = acc[m][n][j] + bv;
        vv = vv > 0.f ? vv : (__expf(vv) - 1.f);
        *reinterpret_cast<unsigned short*>(
            smem + row * 256 + ((c * 2) ^ ((row & 7) << 4))) = f2bf(vv);
      }
    }
  }
  __syncthreads();
  const int r2 = tid >> 1, hf = tid & 1;
  uint4* drow = reinterpret_cast<uint4*>(hbf + (size_t)(m0 + r2) * COUT_ + hf * 64);
  #pragma unroll
  for (int u = 0; u < 8; ++u) {
    int cb = hf * 128 + u * 16;
    drow[u] = *reinterpret_cast<const uint4*>(smem + r2 * 256 + (cb ^ ((r2 & 7) << 4)));
  }
}

// ---------------- pool: CSR scan / fill, then row-major gather ----------

__global__ __launch_bounds__(256) void pool_scan(const int* __restrict__ counts,
                                                 int* __restrict__ offsets,
                                                 int* __restrict__ cursor) {
  __shared__ int part[256];
  const int t = threadIdx.x;
  const int c0 = t * 49;
  int s = 0;
  for (int i = 0; i < 49; ++i) {
    int j = c0 + i;
    if (j < VOUT_) s += counts[j];
  }
  part[t] = s;
  __syncthreads();
  #pragma unroll
  for (int off = 1; off < 256; off <<= 1) {
    int v = (t >= off) ? part[t - off] : 0;
    __syncthreads();
    part[t] += v;
    __syncthreads();
  }
  int run = part[t] - s;                 // exclusive prefix of my chunk
  for (int i = 0; i < 49; ++i) {
    int j = c0 + i;
    if (j < VOUT_) {
      offsets[j] = run; cursor[j] = run;
      run += counts[j];
    }
  }
  if (t == 255) offsets[VOUT_] = part[255];   // == NNZ_
}

__global__ __launch_bounds__(256) void pool_fill(const int* __restrict__ dr,
                                                 const int* __restrict__ dc,
                                                 const float* __restrict__ dd,
                                                 int* __restrict__ cursor,
                                                 int2* __restrict__ elist) {
  int e = blockIdx.x * 256 + threadIdx.x;
  if (e < NNZ_) {
    int slot = atomicAdd(&cursor[dr[e]], 1);
    elist[slot] = make_int2(dc[e], __float_as_int(dd[e]));
  }
}

__global__ __launch_bounds__(256) void pool_rows(const unsigned short* __restrict__ hbf,
                                                 const int* __restrict__ offsets,
                                                 const int2* __restrict__ elist,
                                                 float* __restrict__ out) {
  const int row = blockIdx.x;
  const int bg = threadIdx.x >> 5;     // batch 0..7
  const int lc = threadIdx.x & 31;     // c-quad 0..31
  const int s = offsets[row], e1 = offsets[row + 1];
  const unsigned short* hb = hbf + (size_t)bg * (V_ * COUT_) + lc * 4;
  float4 acc = {0.f, 0.f, 0.f, 0.f};
  for (int e = s; e < e1; ++e) {
    int2 en = elist[e];
    float d = __int_as_float(en.y);
    ushort4 v = *reinterpret_cast<const ushort4*>(hb + (size_t)en.x * COUT_);
    acc.x += d * bf2f(v.x);
    acc.y += d * bf2f(v.y);
    acc.z += d * bf2f(v.z);
    acc.w += d * bf2f(v.w);
  }
  *reinterpret_cast<float4*>(out + ((size_t)bg * VOUT_ + row) * COUT_ + lc * 4) = acc;
}

extern "C" void kernel_launch(void* const* d_in, const int* in_sizes, int n_in,
                              void* d_out, int out_size, void* d_ws, size_t ws_size,
                              hipStream_t stream) {
  const float* x    = (const float*)d_in[0];
  const float* w    = (const float*)d_in[1];
  const float* bias = (const float*)d_in[2];
  const int*   sp   = (const int*)d_in[3];
  const int*   dr   = (const int*)d_in[4];
  const int*   dc   = (const int*)d_in[5];
  const float* dd   = (const float*)d_in[6];
  float* out = (float*)d_out;

  char* ws = (char*)d_ws;
  unsigned short* wfr = (unsigned short*)ws;                       // 147,456 B (frag-major)
  unsigned short* xbf = (unsigned short*)(ws + 147456);            // 51,200,000 B
  unsigned short* hbf = (unsigned short*)(ws + 51347456);          // 102,400,000 B
  int*  counts  = (int*) (ws + 153747456);                         // 50,000 B
  int*  cursor  = (int*) (ws + 153797456);                         // 50,000 B
  int*  offsets = (int*) (ws + 153847456);                         // 50,004 B
  int2* elist   = (int2*)(ws + 153897464);                         // 300,000 B

  hipMemsetAsync(counts, 0, VOUT_ * sizeof(int), stream);
  prep<<<PREP_WBLK + PREP_CBLK + PREP_XBLK, 256, 0, stream>>>(w, wfr, x, xbf, dr, counts);
  pool_scan<<<1, 256, 0, stream>>>(counts, offsets, cursor);
  pool_fill<<<(NNZ_ + 255) / 256, 256, 0, stream>>>(dr, dc, dd, cursor, elist);
  spiral_gemm<<<NWG, 256, 0, stream>>>(xbf, wfr, bias, sp, hbf);
  pool_rows<<<VOUT_, 256, 0, stream>>>(hbf, offsets, elist, out);
}

// Round 9
// 155.478 us; speedup vs baseline: 3.1451x; 1.2639x over previous
//
#include <hip/hip_runtime.h>

#define B_    8
#define V_    50000
#define KNB   9
#define CIN_  64
#define COUT_ 128
#define VOUT_ 12500
#define NNZ_  37500
#define KTOT  576      // KNB*CIN_
#define M_    400000   // B_*V_
#define NWG   3125     // M_/128

typedef short bf16x8 __attribute__((ext_vector_type(8)));
typedef float f32x4  __attribute__((ext_vector_type(4)));

#define AS1 __attribute__((address_space(1)))
#define AS3 __attribute__((address_space(3)))

__device__ __forceinline__ unsigned short f2bf(float f) {
  unsigned u = __float_as_uint(f);
  u += 0x7fffu + ((u >> 16) & 1u);          // RNE
  return (unsigned short)(u >> 16);
}
__device__ __forceinline__ float bf2f(unsigned short u) {
  return __uint_as_float((unsigned)u << 16);
}

__device__ __forceinline__ void gld_lds16(const void* g, void* l) {
  __builtin_amdgcn_global_load_lds((const AS1 unsigned*)g, (AS3 unsigned*)l, 16, 0, 0);
}

// Fused prep: [0,36) W->frag-major bf16; [36,183) pool bucket-fill (atomic cursor);
// [183,2231) x fp32->bf16 (grid-stride).
#define PREP_WBLK 36
#define PREP_FBLK 147
#define PREP_XBLK 2048
__global__ __launch_bounds__(256) void prep(const float* __restrict__ w,
                                            unsigned short* __restrict__ wfr,
                                            const float* __restrict__ x,
                                            unsigned short* __restrict__ xbf,
                                            const int* __restrict__ dr,
                                            const int* __restrict__ dc,
                                            const float* __restrict__ dd,
                                            int* __restrict__ cursor,
                                            int2* __restrict__ elist) {
  const int bid = blockIdx.x;
  if (bid < PREP_WBLK) {
    // W -> MFMA-fragment-major: chunk i holds, for lane=i&63, n=(i>>6)&3,
    // wc=(i>>8)&1, ks=(i>>9)&1, t=i>>10:
    //   W[col=wc*64+n*16+(lane&15)][k=t*64+ks*32+(lane>>4)*8 .. +8]
    int i = bid * 256 + threadIdx.x;        // 0..9215
    int lane = i & 63, n = (i >> 6) & 3, wc = (i >> 8) & 1, ks = (i >> 9) & 1, t = i >> 10;
    int col = wc * 64 + n * 16 + (lane & 15);
    int k0 = t * 64 + ks * 32 + (lane >> 4) * 8;
    const float* src = w + (size_t)col * KTOT + k0;
    float4 f0 = reinterpret_cast<const float4*>(src)[0];
    float4 f1 = reinterpret_cast<const float4*>(src)[1];
    uint4 o;
    o.x = (unsigned)f2bf(f0.x) | ((unsigned)f2bf(f0.y) << 16);
    o.y = (unsigned)f2bf(f0.z) | ((unsigned)f2bf(f0.w) << 16);
    o.z = (unsigned)f2bf(f1.x) | ((unsigned)f2bf(f1.y) << 16);
    o.w = (unsigned)f2bf(f1.z) | ((unsigned)f2bf(f1.w) << 16);
    reinterpret_cast<uint4*>(wfr)[i] = o;
  } else if (bid < PREP_WBLK + PREP_FBLK) {
    int e = (bid - PREP_WBLK) * 256 + threadIdx.x;
    if (e < NNZ_) {
      int r = dr[e];
      int slot = atomicAdd(&cursor[r], 1);
      if (slot < 32) elist[r * 32 + slot] = make_int2(dc[e], __float_as_int(dd[e]));
    }
  } else {
    const int nq = B_ * V_ * CIN_ / 4;      // 6.4M float4 quads
    for (int q = (bid - PREP_WBLK - PREP_FBLK) * 256 + threadIdx.x; q < nq;
         q += PREP_XBLK * 256) {
      float4 f = reinterpret_cast<const float4*>(x)[q];
      ushort4 o;
      o.x = f2bf(f.x); o.y = f2bf(f.y); o.z = f2bf(f.z); o.w = f2bf(f.w);
      reinterpret_cast<ushort4*>(xbf)[q] = o;
    }
  }
}

// h = elu(gather(x) @ W^T + bias). 128x128 tile, 4 waves, BK=64.
// Counted-vmcnt pipeline with a CLEAN VMEM queue:
//   - all 1152 spiral indices cached in LDS up-front (idx reads are lgkm, not vmcnt)
//   - per unrolled iter t, VMEM issue order: B(t+1) x8 reg-loads, then A(t+2) x4 gld_lds
//   - steady entry state: [A(t)4, B(t)8, A(t+1)4] outstanding -> s_waitcnt vmcnt(16)
//     (t=7: 12, t=8: 0). Raw s_barrier; lgkmcnt(0)+sched_barrier before each barrier.
//   - A: 3 LDS buffers (2 iters to land, covers ~900cyc HBM gather)
//   - B: two named register banks, statically swapped (1 iter to land, covers L2)
// LDS 52.5KB -> 3 blocks/CU (= measured residency at R8, so nothing lost);
// launch_bounds(256,3) -> VGPR cap ~170, no spill (R7 lesson: the 2nd arg is a
// register-budget contract).
struct GemmSM { char A[3][16384]; int spc[1152]; };

__global__ __launch_bounds__(256, 3) void spiral_gemm(
    const unsigned short* __restrict__ xbf, const unsigned short* __restrict__ wfr,
    const float* __restrict__ bias, const int* __restrict__ sp,
    unsigned short* __restrict__ hbf)
{
  __shared__ GemmSM smv;
  GemmSM* sm = &smv;

  // ---- bijective XCD swizzle (nwg=3125: q=390, r=5)
  const int q_ = NWG / 8, r_ = NWG % 8;
  const int xcd = blockIdx.x & 7, pos = blockIdx.x >> 3;
  const int nbid = (xcd < r_) ? xcd * (q_ + 1) + pos
                              : r_ * (q_ + 1) + (xcd - r_) * q_ + pos;

  const int tid  = threadIdx.x;
  const int m0   = nbid * 128;
  const int wave = tid >> 6;
  const int lane = tid & 63;

  // ---- cache all spiral indices for this tile's 128 rows in LDS
  for (int i = tid; i < 128 * KNB; i += 256) {
    int row = i / 9, j = i - row * 9;
    int m = m0 + row;
    int b = m / V_;
    int v = m - b * V_;
    sm->spc[i] = sp[v * KNB + j];
  }

  // ---- staging geometry: 4 rounds x 32 rows, 8 lanes x 16B chunks per 128B row
  const int rrow  = tid >> 3;                       // 0..31
  const int chunkoff = (((tid & 7) ^ (rrow & 7)) << 4); // inverse-swizzled source chunk
  unsigned boff[4];
  int sbase[4], ldso[4];
  #pragma unroll
  for (int r = 0; r < 4; ++r) {
    int row = r * 32 + rrow;
    int m = m0 + row;
    int b = m / V_;
    boff[r]  = (unsigned)b * (V_ * CIN_ * 2);       // byte offset of batch slice
    sbase[r] = row * KNB;
    ldso[r]  = (r * 32 + wave * 8) * 128;
  }

  // ---- compute geometry
  const int wr = wave >> 1, wc = wave & 1;
  const int lr = lane & 15, lg = lane >> 4;
  const bf16x8* wbase = (const bf16x8*)wfr + wc * 256 + lane;   // +((t*2+ks)*512 + n*64)

  f32x4 acc[4][4];
  #pragma unroll
  for (int i = 0; i < 4; ++i)
    #pragma unroll
    for (int j = 0; j < 4; ++j)
      acc[i][j] = (f32x4){0.f, 0.f, 0.f, 0.f};

  auto stageA = [&](int bi, int t) {
    char* Ab = sm->A[bi];
    #pragma unroll
    for (int r = 0; r < 4; ++r) {
      int idx = sm->spc[sbase[r] + t];              // LDS read (lgkm domain)
      unsigned off = boff[r] + (unsigned)idx * 128u + (unsigned)chunkoff;
      gld_lds16((const char*)xbf + off, Ab + ldso[r]);
    }
  };

  bf16x8 b0[2][4], b1[2][4];
  auto loadB = [&](bf16x8 (&bk)[2][4], int t) {
    #pragma unroll
    for (int ks = 0; ks < 2; ++ks)
      #pragma unroll
      for (int n = 0; n < 4; ++n)
        bk[ks][n] = wbase[(t * 2 + ks) * 512 + n * 64];
  };

  // ---- prologue (spc visible to all, then issue order: B(0)x8, A(0)x4, A(1)x4)
  __syncthreads();
  loadB(b0, 0);
  stageA(0, 0);
  stageA(1, 1);

#define GITER(T, BC, BN)                                                        \
  do {                                                                          \
    asm volatile("s_waitcnt vmcnt(%0)" :: "i"((T) <= 6 ? 16 : ((T) == 7 ? 12 : 0)) : "memory"); \
    __builtin_amdgcn_sched_barrier(0);                                          \
    __builtin_amdgcn_s_barrier();                                               \
    if ((T) + 1 < KNB) loadB(BN, (T) + 1);                                      \
    __builtin_amdgcn_sched_barrier(0);                                          \
    if ((T) + 2 < KNB) stageA(((T) + 2) % 3, (T) + 2);                          \
    __builtin_amdgcn_sched_barrier(0);                                          \
    {                                                                           \
      const char* Ab = sm->A[(T) % 3];                                          \
      _Pragma("unroll")                                                         \
      for (int ks = 0; ks < 2; ++ks) {                                          \
        const int kb = ks * 64 + lg * 16;                                       \
        bf16x8 af[4];                                                           \
        _Pragma("unroll")                                                       \
        for (int m = 0; m < 4; ++m) {                                           \
          int row = wr * 64 + m * 16 + lr;                                      \
          af[m] = *reinterpret_cast<const bf16x8*>(                             \
              Ab + row * 128 + (kb ^ ((row & 7) << 4)));                        \
        }                                                                       \
        __builtin_amdgcn_s_setprio(1);                                          \
        _Pragma("unroll")                                                       \
        for (int m = 0; m < 4; ++m)                                             \
          _Pragma("unroll")                                                     \
          for (int n = 0; n < 4; ++n)                                           \
            acc[m][n] = __builtin_amdgcn_mfma_f32_16x16x32_bf16(                \
                af[m], BC[ks][n], acc[m][n], 0, 0, 0);                          \
        __builtin_amdgcn_s_setprio(0);                                          \
      }                                                                         \
    }                                                                           \
    asm volatile("s_waitcnt lgkmcnt(0)" ::: "memory");                          \
    __builtin_amdgcn_sched_barrier(0);                                          \
  } while (0)

  GITER(0, b0, b1);
  GITER(1, b1, b0);
  GITER(2, b0, b1);
  GITER(3, b1, b0);
  GITER(4, b0, b1);
  GITER(5, b1, b0);
  GITER(6, b0, b1);
  GITER(7, b1, b0);
  GITER(8, b0, b1);
#undef GITER

  // ---- epilogue: bias + ELU -> bf16 into swizzled hs over A[0..1] (32KB),
  //      then coalesced 16B global stores. Last reads of A[0]/A[1] retired
  //      before the iter-8 barrier; iter-8 MFMAs read A[2] (disjoint region).
  unsigned short* dummy = nullptr; (void)dummy;
  char* hsb = (char*)sm;
  #pragma unroll
  for (int n = 0; n < 4; ++n) {
    const int c = wc * 64 + n * 16 + lr;
    const float bv = bias[c];
    #pragma unroll
    for (int m = 0; m < 4; ++m) {
      const int row0 = wr * 64 + m * 16 + lg * 4;
      #pragma unroll
      for (int j = 0; j < 4; ++j) {
        const int row = row0 + j;
        float vv = acc[m][n][j] + bv;
        vv = vv > 0.f ? vv : (__expf(vv) - 1.f);
        *reinterpret_cast<unsigned short*>(
            hsb + row * 256 + ((c * 2) ^ ((row & 7) << 4))) = f2bf(vv);
      }
    }
  }
  __syncthreads();
  const int r2 = tid >> 1, hf = tid & 1;
  uint4* drow = reinterpret_cast<uint4*>(hbf + (size_t)(m0 + r2) * COUT_ + hf * 64);
  #pragma unroll
  for (int u = 0; u < 8; ++u) {
    int cb = hf * 128 + u * 16;
    drow[u] = *reinterpret_cast<const uint4*>(hsb + r2 * 256 + (cb ^ ((r2 & 7) << 4)));
  }
}

// One block per output row; 8 b-groups x 32 lanes; bucketed entries (cap 32).
__global__ __launch_bounds__(256) void pool_rows(const unsigned short* __restrict__ hbf,
                                                 const int* __restrict__ cursor,
                                                 const int2* __restrict__ elist,
                                                 float* __restrict__ out) {
  const int row = blockIdx.x;
  const int bg = threadIdx.x >> 5;     // batch 0..7
  const int lc = threadIdx.x & 31;     // c-quad 0..31
  int cnt = cursor[row];
  cnt = cnt < 32 ? cnt : 32;
  const unsigned short* hb = hbf + (size_t)bg * (V_ * COUT_) + lc * 4;
  float4 acc = {0.f, 0.f, 0.f, 0.f};
  for (int e = 0; e < cnt; ++e) {
    int2 en = elist[row * 32 + e];
    float d = __int_as_float(en.y);
    ushort4 v = *reinterpret_cast<const ushort4*>(hb + (size_t)en.x * COUT_);
    acc.x += d * bf2f(v.x);
    acc.y += d * bf2f(v.y);
    acc.z += d * bf2f(v.z);
    acc.w += d * bf2f(v.w);
  }
  *reinterpret_cast<float4*>(out + ((size_t)bg * VOUT_ + row) * COUT_ + lc * 4) = acc;
}

extern "C" void kernel_launch(void* const* d_in, const int* in_sizes, int n_in,
                              void* d_out, int out_size, void* d_ws, size_t ws_size,
                              hipStream_t stream) {
  const float* x    = (const float*)d_in[0];
  const float* w    = (const float*)d_in[1];
  const float* bias = (const float*)d_in[2];
  const int*   sp   = (const int*)d_in[3];
  const int*   dr   = (const int*)d_in[4];
  const int*   dc   = (const int*)d_in[5];
  const float* dd   = (const float*)d_in[6];
  float* out = (float*)d_out;

  char* ws = (char*)d_ws;
  unsigned short* wfr = (unsigned short*)ws;                       // 147,456 B (frag-major)
  unsigned short* xbf = (unsigned short*)(ws + 147456);            // 51,200,000 B
  unsigned short* hbf = (unsigned short*)(ws + 51347456);          // 102,400,000 B
  int*  cursor  = (int*) (ws + 153747456);                         // 50,000 B
  int2* elist   = (int2*)(ws + 153797456);                         // 3,200,000 B

  hipMemsetAsync(cursor, 0, VOUT_ * sizeof(int), stream);
  prep<<<PREP_WBLK + PREP_FBLK + PREP_XBLK, 256, 0, stream>>>(
      w, wfr, x, xbf, dr, dc, dd, cursor, elist);
  spiral_gemm<<<NWG, 256, 0, stream>>>(xbf, wfr, bias, sp, hbf);
  pool_rows<<<VOUT_, 256, 0, stream>>>(hbf, cursor, elist, out);
}